// Round 1
// baseline (723.793 us; speedup 1.0000x reference)
//
#include <hip/hip_runtime.h>
#include <hip/hip_bf16.h>
#include <math.h>

#define NBATCH 16
#define NW 64
#define WA 49
#define NTOK (NBATCH*NW*WA)   // 50176
#define CCH 384
#define HIDDEN 1536

typedef __attribute__((ext_vector_type(8))) short short8;
typedef __attribute__((ext_vector_type(4))) float floatx4;

static __device__ __forceinline__ short f2bf(float f){
  unsigned u = __float_as_uint(f);
  unsigned r = (u + 0x7fff + ((u>>16)&1)) >> 16;
  return (short)r;
}
static __device__ __forceinline__ float bf2f(short s){
  return __uint_as_float(((unsigned)(unsigned short)s)<<16);
}

// token index -> pixel index (same map for LN1 gather and proj scatter)
static __device__ __forceinline__ int tok2pix(int t){
  int b = t / (NW*WA);
  int rem = t % (NW*WA);
  int w = rem / WA, a = rem % WA;
  int hs = (w>>3)*7 + a/7;
  int ws = (w&7)*7 + a%7;
  int hp = hs + 3; if (hp >= 56) hp -= 56;
  int wp = ws + 3; if (wp >= 56) wp -= 56;
  return (b*56 + hp)*56 + wp;
}

// ---- weight transpose + fp32->bf16 convert: W[K,N] -> Wt[N,K] ----
__global__ void wtconv(const float* __restrict__ W, short* __restrict__ Wt, int K, int N){
  int i = blockIdx.x*256 + threadIdx.x;
  if (i >= K*N) return;
  int k = i / N, n = i % N;
  Wt[(size_t)n*K + k] = f2bf(W[i]);
}

// ---- LayerNorm (one wave per token). MAP=1: gather via tok2pix (LN1+shift+window) ----
template<int MAP>
__global__ __launch_bounds__(256) void ln_kernel(const float* __restrict__ x,
    const float* __restrict__ g, const float* __restrict__ bta, short* __restrict__ out){
  int wid = threadIdx.x>>6, lane = threadIdx.x&63;
  int t = blockIdx.x*4 + wid;
  const float* row = x + (size_t)(MAP ? tok2pix(t) : t)*CCH;
  float v[6]; float s=0.f, ss=0.f;
  #pragma unroll
  for (int i=0;i<6;i++){ float f=row[lane+64*i]; v[i]=f; s+=f; ss+=f*f; }
  #pragma unroll
  for (int off=32; off; off>>=1){ s += __shfl_xor(s,off); ss += __shfl_xor(ss,off); }
  float mean = s*(1.f/384.f);
  float var  = ss*(1.f/384.f) - mean*mean;
  float inv  = rsqrtf(var + 1e-5f);
  short* orow = out + (size_t)t*CCH;
  #pragma unroll
  for (int i=0;i<6;i++){ int c=lane+64*i; orow[c] = f2bf((v[i]-mean)*inv*g[c]+bta[c]); }
}

// ---- bf16 MFMA GEMM: C[M,N] = A[M,K] * Bt[N,K]^T + bias, with fused epilogues ----
// EPI 0: store bf16 (qkv)      EPI 1: proj -> y[pix] = x[pix] + v
// EPI 2: gelu -> bf16 (fc1)    EPI 3: out[t] = res[t] + v (fc2, fp32)
template<int EPI>
__global__ __launch_bounds__(256) void gemm_bf16(const short* __restrict__ A,
    const short* __restrict__ Bt, const float* __restrict__ bias,
    const float* __restrict__ res, void* __restrict__ outp,
    int M, int N, int K)
{
  __shared__ short As[128][48];
  __shared__ short Bs[128][48];
  const int tid = threadIdx.x, lane = tid & 63, wid = tid >> 6;
  const int m0 = blockIdx.y*128, n0 = blockIdx.x*128;
  const int wr = (wid>>1)*64, wc = (wid&1)*64;
  const int fr = lane & 15, fg = lane >> 4;
  floatx4 acc[4][4];
  #pragma unroll
  for (int m=0;m<4;m++)
    #pragma unroll
    for (int n=0;n<4;n++) acc[m][n] = (floatx4){0.f,0.f,0.f,0.f};
  const int srow = tid>>2, sseg = (tid&3)*8;
  for (int k0 = 0; k0 < K; k0 += 32) {
    #pragma unroll
    for (int p=0;p<2;p++){
      int r = srow + p*64;
      *(short8*)&As[r][sseg] = *(const short8*)&A [(size_t)(m0+r)*K + k0 + sseg];
      *(short8*)&Bs[r][sseg] = *(const short8*)&Bt[(size_t)(n0+r)*K + k0 + sseg];
    }
    __syncthreads();
    short8 af[4], bfr[4];
    #pragma unroll
    for (int m=0;m<4;m++) af[m]  = *(const short8*)&As[wr + m*16 + fr][fg*8];
    #pragma unroll
    for (int n=0;n<4;n++) bfr[n] = *(const short8*)&Bs[wc + n*16 + fr][fg*8];
    #pragma unroll
    for (int m=0;m<4;m++)
      #pragma unroll
      for (int n=0;n<4;n++)
        acc[m][n] = __builtin_amdgcn_mfma_f32_16x16x32_bf16(af[m], bfr[n], acc[m][n], 0,0,0);
    __syncthreads();
  }
  #pragma unroll
  for (int n=0;n<4;n++){
    int gc = n0 + wc + n*16 + fr;
    float bv = bias[gc];
    #pragma unroll
    for (int m=0;m<4;m++){
      int gr0 = m0 + wr + m*16 + fg*4;
      #pragma unroll
      for (int i=0;i<4;i++){
        int R = gr0 + i;
        float v = acc[m][n][i] + bv;
        if (EPI==0){
          ((short*)outp)[(size_t)R*N + gc] = f2bf(v);
        } else if (EPI==1){
          int p = tok2pix(R); size_t idx=(size_t)p*CCH+gc;
          ((float*)outp)[idx] = res[idx] + v;
        } else if (EPI==2){
          float gg = 0.5f*v*(1.f+erff(v*0.70710678118654752f));
          ((short*)outp)[(size_t)R*N+gc] = f2bf(gg);
        } else {
          size_t idx=(size_t)R*CCH+gc;
          ((float*)outp)[idx] = res[idx] + v;
        }
      }
    }
  }
}

// ---- windowed attention: one block per window, wave w handles heads w, w+4, w+8 ----
__global__ __launch_bounds__(256) void attn_kernel(const short* __restrict__ qkv,
    const float* __restrict__ rel_bias, short* __restrict__ attnout)
{
  __shared__ float Kl[4][49][32];
  __shared__ float Vl[4][49][32];
  __shared__ float S[4][49][50];
  __shared__ int grp[49];
  const int wi = blockIdx.x;
  const int wid = threadIdx.x>>6, lane = threadIdx.x&63;
  const int w = wi & 63, wh = w>>3, wwn = w&7;
  if (threadIdx.x < 49){
    int ai = threadIdx.x/7, aj = threadIdx.x%7;
    int hs = wh*7+ai, ws = wwn*7+aj;
    int gh = hs<49?0:(hs<53?1:2);
    int gw = ws<49?0:(ws<53?1:2);
    grp[threadIdx.x] = gh*3+gw;
  }
  __syncthreads();
  const size_t tbase = (size_t)wi*49;
  for (int hi=0; hi<3; ++hi){
    int h = wid + hi*4;
    for (int idx = lane; idx < 1568; idx += 64){
      int j = idx>>5, d = idx&31;
      const short* rowp = qkv + (tbase+j)*1152;
      Kl[wid][j][d] = bf2f(rowp[384 + h*32 + d]);
      Vl[wid][j][d] = bf2f(rowp[768 + h*32 + d]);
    }
    __syncthreads();
    int r = lane;
    if (r < 49){
      float q[32];
      const short* qrow = qkv + (tbase+r)*1152 + h*32;
      #pragma unroll
      for (int d=0;d<32;d++) q[d]=bf2f(qrow[d]);
      int gr = grp[r];
      int ri_ = r/7, rj_ = r%7;
      float mx = -1e30f;
      for (int j=0;j<49;j++){
        const float4* kr = (const float4*)Kl[wid][j];
        float s0=0,s1=0,s2=0,s3=0;
        #pragma unroll
        for (int dq=0;dq<8;dq++){
          float4 kv = kr[dq];
          s0 += q[dq*4+0]*kv.x; s1 += q[dq*4+1]*kv.y;
          s2 += q[dq*4+2]*kv.z; s3 += q[dq*4+3]*kv.w;
        }
        float s = ((s0+s1)+(s2+s3)) * 0.17677669529663687f;
        int ji_=j/7, jj_=j%7;
        int bidx = (ri_-ji_+6)*13 + (rj_-jj_+6);
        s += rel_bias[bidx*12 + h];
        if (grp[j]!=gr) s -= 100.f;
        S[wid][r][j]=s;
        mx = fmaxf(mx,s);
      }
      float sum=0.f;
      for (int j=0;j<49;j++){
        float e=__expf(S[wid][r][j]-mx);
        S[wid][r][j]=e; sum+=e;
      }
      float inv=1.f/sum;
      float o[32];
      #pragma unroll
      for (int d=0;d<32;d++) o[d]=0.f;
      for (int j=0;j<49;j++){
        float p = S[wid][r][j];
        const float4* vr = (const float4*)Vl[wid][j];
        #pragma unroll
        for (int dq=0;dq<8;dq++){
          float4 vv=vr[dq];
          o[dq*4+0]+=p*vv.x; o[dq*4+1]+=p*vv.y;
          o[dq*4+2]+=p*vv.z; o[dq*4+3]+=p*vv.w;
        }
      }
      short* orow = attnout + (tbase+r)*384 + h*32;
      #pragma unroll
      for (int d=0;d<32;d++) orow[d]=f2bf(o[d]*inv);
    }
    __syncthreads();
  }
}

extern "C" void kernel_launch(void* const* d_in, const int* in_sizes, int n_in,
                              void* d_out, int out_size, void* d_ws, size_t ws_size,
                              hipStream_t stream)
{
  const float* x      = (const float*)d_in[0];
  const float* n1g    = (const float*)d_in[1];
  const float* n1b    = (const float*)d_in[2];
  const float* qkv_w  = (const float*)d_in[3];
  const float* qkv_b  = (const float*)d_in[4];
  const float* relb   = (const float*)d_in[5];
  const float* proj_w = (const float*)d_in[6];
  const float* proj_b = (const float*)d_in[7];
  const float* n2g    = (const float*)d_in[8];
  const float* n2b    = (const float*)d_in[9];
  const float* fc1_w  = (const float*)d_in[10];
  const float* fc1_b  = (const float*)d_in[11];
  const float* fc2_w  = (const float*)d_in[12];
  const float* fc2_b  = (const float*)d_in[13];

  char* ws = (char*)d_ws;
  const size_t SZ_XW  = (size_t)NTOK*CCH*2;      // 38,535,168  (xw, later hin)
  const size_t SZ_QKV = (size_t)NTOK*1152*2;     // 115,605,504 (qkv, later h low part)
  const size_t SZ_ATT = SZ_XW;                   // attnout, later h high part
  const size_t SZ_Y   = (size_t)NTOK*CCH*4;      // 77,070,336

  short* xw    = (short*)(ws);
  short* qkvb  = (short*)(ws + SZ_XW);
  short* att   = (short*)(ws + SZ_XW + SZ_QKV);
  float* y     = (float*)(ws + SZ_XW + SZ_QKV + SZ_ATT);
  short* wbuf  = (short*)(ws + SZ_XW + SZ_QKV + SZ_ATT + SZ_Y);
  short* qkvWt = wbuf;                           // [1152][384]
  short* projWt= qkvWt + (size_t)1152*384;       // [384][384]
  short* fc1Wt = projWt + (size_t)384*384;       // [1536][384]
  short* fc2Wt = fc1Wt + (size_t)1536*384;       // [384][1536]
  short* hbuf  = qkvb;                           // [NTOK][1536] (reuses qkv+att)
  short* hin   = xw;                             // [NTOK][384]  (reuses xw)

  wtconv<<<dim3((384*1152+255)/256), dim3(256), 0, stream>>>(qkv_w, qkvWt, 384, 1152);
  wtconv<<<dim3((384*384 +255)/256), dim3(256), 0, stream>>>(proj_w, projWt, 384, 384);
  wtconv<<<dim3((384*1536+255)/256), dim3(256), 0, stream>>>(fc1_w, fc1Wt, 384, 1536);
  wtconv<<<dim3((1536*384+255)/256), dim3(256), 0, stream>>>(fc2_w, fc2Wt, 1536, 384);

  ln_kernel<1><<<dim3(NTOK/4), dim3(256), 0, stream>>>(x, n1g, n1b, xw);
  gemm_bf16<0><<<dim3(1152/128, NTOK/128), dim3(256), 0, stream>>>(xw, qkvWt, qkv_b, nullptr, qkvb, NTOK, 1152, 384);
  attn_kernel<<<dim3(NBATCH*NW), dim3(256), 0, stream>>>(qkvb, relb, att);
  gemm_bf16<1><<<dim3(384/128, NTOK/128), dim3(256), 0, stream>>>(att, projWt, proj_b, x, y, NTOK, 384, 384);
  ln_kernel<0><<<dim3(NTOK/4), dim3(256), 0, stream>>>(y, n2g, n2b, hin);
  gemm_bf16<2><<<dim3(1536/128, NTOK/128), dim3(256), 0, stream>>>(hin, fc1Wt, fc1_b, nullptr, hbuf, NTOK, 1536, 384);
  gemm_bf16<3><<<dim3(384/128, NTOK/128), dim3(256), 0, stream>>>(hbuf, fc2Wt, fc2_b, y, d_out, NTOK, 384, 1536);
}

// Round 2
// 564.069 us; speedup vs baseline: 1.2832x; 1.2832x over previous
//
#include <hip/hip_runtime.h>
#include <hip/hip_bf16.h>
#include <math.h>

#define NBATCH 16
#define NW 64
#define WA 49
#define NTOK (NBATCH*NW*WA)   // 50176
#define CCH 384
#define HIDDEN 1536

typedef __attribute__((ext_vector_type(8))) short short8;
typedef __attribute__((ext_vector_type(4))) float floatx4;

static __device__ __forceinline__ short f2bf(float f){
  unsigned u = __float_as_uint(f);
  unsigned r = (u + 0x7fff + ((u>>16)&1)) >> 16;
  return (short)r;
}
static __device__ __forceinline__ float bf2f(short s){
  return __uint_as_float(((unsigned)(unsigned short)s)<<16);
}

static __device__ __forceinline__ void gload16(const void* g, void* l){
  __builtin_amdgcn_global_load_lds(
      (const __attribute__((address_space(1))) void*)g,
      (__attribute__((address_space(3))) void*)l, 16, 0, 0);
}

// token index -> pixel index (same map for LN1 gather and proj scatter)
static __device__ __forceinline__ int tok2pix(int t){
  int b = t / (NW*WA);
  int rem = t % (NW*WA);
  int w = rem / WA, a = rem % WA;
  int hs = (w>>3)*7 + a/7;
  int ws = (w&7)*7 + a%7;
  int hp = hs + 3; if (hp >= 56) hp -= 56;
  int wp = ws + 3; if (wp >= 56) wp -= 56;
  return (b*56 + hp)*56 + wp;
}

// ---- weight transpose + fp32->bf16 convert: W[K,N] -> Wt[N,K] ----
__global__ void wtconv(const float* __restrict__ W, short* __restrict__ Wt, int K, int N){
  int i = blockIdx.x*256 + threadIdx.x;
  if (i >= K*N) return;
  int k = i / N, n = i % N;
  Wt[(size_t)n*K + k] = f2bf(W[i]);
}

// ---- LayerNorm (one wave per token). MAP=1: gather via tok2pix (LN1+shift+window) ----
template<int MAP>
__global__ __launch_bounds__(256) void ln_kernel(const float* __restrict__ x,
    const float* __restrict__ g, const float* __restrict__ bta, short* __restrict__ out){
  int wid = threadIdx.x>>6, lane = threadIdx.x&63;
  int t = blockIdx.x*4 + wid;
  const float* row = x + (size_t)(MAP ? tok2pix(t) : t)*CCH;
  float v[6]; float s=0.f, ss=0.f;
  #pragma unroll
  for (int i=0;i<6;i++){ float f=row[lane+64*i]; v[i]=f; s+=f; ss+=f*f; }
  #pragma unroll
  for (int off=32; off; off>>=1){ s += __shfl_xor(s,off); ss += __shfl_xor(ss,off); }
  float mean = s*(1.f/384.f);
  float var  = ss*(1.f/384.f) - mean*mean;
  float inv  = rsqrtf(var + 1e-5f);
  short* orow = out + (size_t)t*CCH;
  #pragma unroll
  for (int i=0;i<6;i++){ int c=lane+64*i; orow[c] = f2bf((v[i]-mean)*inv*g[c]+bta[c]); }
}

// ---- bf16 MFMA GEMM (m97 structure): C[M,N] = A[M,K]*Bt[N,K]^T + bias, fused epilogues ----
// EPI 0: store bf16 (qkv)      EPI 1: proj -> y[pix] = x[pix] + v
// EPI 2: gelu -> bf16 (fc1)    EPI 3: out[t] = res[t] + v (fc2, fp32)
template<int EPI>
__global__ __launch_bounds__(256) void gemm_bf16(const short* __restrict__ A,
    const short* __restrict__ Bt, const float* __restrict__ bias,
    const float* __restrict__ res, void* __restrict__ outp,
    int M, int N, int K)
{
  __shared__ short As[128][32];
  __shared__ short Bs[128][32];
  const int tid = threadIdx.x, lane = tid & 63, wid = tid >> 6;
  const int m0 = blockIdx.y*128, n0 = blockIdx.x*128;
  const int wr = (wid>>1)*64, wc = (wid&1)*64;
  const int fr = lane & 15, fg = lane >> 4;
  floatx4 acc[4][4];
  #pragma unroll
  for (int m=0;m<4;m++)
    #pragma unroll
    for (int n=0;n<4;n++) acc[m][n] = (floatx4){0.f,0.f,0.f,0.f};

  const int srow = wid*32 + (lane>>2);
  const int scol = (lane&3)*8;
  const short* gA = A  + (size_t)(m0+srow)*K + scol;
  const short* gB = Bt + (size_t)(n0+srow)*K + scol;
  short* lA0 = &As[wid*32][0];
  short* lA1 = &As[wid*32+16][0];
  short* lB0 = &Bs[wid*32][0];
  short* lB1 = &Bs[wid*32+16][0];
  const size_t row16 = (size_t)16*K;

  for (int k0 = 0; k0 < K; k0 += 32) {
    gload16(gA + k0,         lA0);
    gload16(gA + k0 + row16, lA1);
    gload16(gB + k0,         lB0);
    gload16(gB + k0 + row16, lB1);
    __syncthreads();
    short8 af[4], bfr[4];
    #pragma unroll
    for (int m=0;m<4;m++) af[m]  = *(const short8*)&As[wr + m*16 + fr][fg*8];
    #pragma unroll
    for (int n=0;n<4;n++) bfr[n] = *(const short8*)&Bs[wc + n*16 + fr][fg*8];
    #pragma unroll
    for (int m=0;m<4;m++)
      #pragma unroll
      for (int n=0;n<4;n++)
        acc[m][n] = __builtin_amdgcn_mfma_f32_16x16x32_bf16(af[m], bfr[n], acc[m][n], 0,0,0);
    __syncthreads();
  }
  #pragma unroll
  for (int n=0;n<4;n++){
    int gc = n0 + wc + n*16 + fr;
    float bv = bias[gc];
    #pragma unroll
    for (int m=0;m<4;m++){
      int gr0 = m0 + wr + m*16 + fg*4;
      #pragma unroll
      for (int i=0;i<4;i++){
        int R = gr0 + i;
        float v = acc[m][n][i] + bv;
        if (EPI==0){
          ((short*)outp)[(size_t)R*N + gc] = f2bf(v);
        } else if (EPI==1){
          int p = tok2pix(R); size_t idx=(size_t)p*CCH+gc;
          ((float*)outp)[idx] = res[idx] + v;
        } else if (EPI==2){
          float gg = 0.5f*v*(1.f+erff(v*0.70710678118654752f));
          ((short*)outp)[(size_t)R*N+gc] = f2bf(gg);
        } else {
          size_t idx=(size_t)R*CCH+gc;
          ((float*)outp)[idx] = res[idx] + v;
        }
      }
    }
  }
}

// ---- MFMA windowed attention: block = window, wave w -> heads w, w+4, w+8 ----
// Per (window,head): S = Q*K^T (64x64 padded, 16 MFMAs), bias+mask+softmax in-register,
// P -> bf16 via padded LDS, O = P*V^T-from-LDS (16 MFMAs).
__global__ __launch_bounds__(256) void attn_mfma(const short* __restrict__ qkv,
    const float* __restrict__ rel_bias, short* __restrict__ attnout)
{
  __shared__ short Pl[4][64][68];
  __shared__ short Vt[4][32][68];
  __shared__ float lb[4][169];
  __shared__ int grp[64];
  const int wi = blockIdx.x;
  const int wid = threadIdx.x>>6, lane = threadIdx.x&63;
  const int fr = lane&15, fg = lane>>4;
  const int w = wi & 63, wh = w>>3, ww = w&7;
  if (threadIdx.x < 64){
    int t = threadIdx.x;
    int gv = 0;
    if (t < 49){
      int ai = t/7, aj = t%7;
      int hs = wh*7+ai, ws = ww*7+aj;
      int gh = hs<49?0:(hs<53?1:2);
      int gw = ws<49?0:(ws<53?1:2);
      gv = gh*3+gw;
    } else gv = -1;
    grp[t] = gv;
  }
  // zero the padding columns of Vt (j=49..63) once; persists across heads
  for (int t = lane; t < 32*15; t += 64){
    int d = t/15, j = 49 + t - d*15;
    Vt[wid][d][j] = 0;
  }
  __syncthreads();
  const size_t tbase = (size_t)wi*49;
  const float SCALE = 0.17677669529663687f;

  for (int hi=0; hi<3; ++hi){
    const int h = hi*4 + wid;
    // stage rel-bias slice for this head
    for (int t = lane; t < 169; t += 64) lb[wid][t] = rel_bias[t*12 + h];
    // stage V transposed: Vt[d][j] = V[j][d]
    for (int t = lane; t < 196; t += 64){
      int j = t>>2, d0 = (t&3)*8;
      short8 vv = *(const short8*)&qkv[(tbase+j)*1152 + 768 + h*32 + d0];
      #pragma unroll
      for (int s=0;s<8;s++) Vt[wid][d0+s][j] = vv[s];
    }
    // Q,K fragments straight from global (L2-hot), zero-padded rows >= 49
    short8 zf = {};
    short8 aq[4], bk[4];
    #pragma unroll
    for (int m=0;m<4;m++){
      int r = m*16+fr;
      aq[m] = (r<49) ? *(const short8*)&qkv[(tbase+r)*1152       + h*32 + fg*8] : zf;
      bk[m] = (r<49) ? *(const short8*)&qkv[(tbase+r)*1152 + 384 + h*32 + fg*8] : zf;
    }
    __syncthreads();   // (1) Vt/lb visible

    // S = Q*K^T : acc layout sc[m][n][i] = S[m*16+fg*4+i][n*16+fr]
    floatx4 sc[4][4];
    #pragma unroll
    for (int m=0;m<4;m++)
      #pragma unroll
      for (int n=0;n<4;n++)
        sc[m][n] = __builtin_amdgcn_mfma_f32_16x16x32_bf16(aq[m], bk[n], (floatx4){0.f,0.f,0.f,0.f}, 0,0,0);

    // per-column (k-token) metadata
    int ciC[4], cjC[4], gC[4], cvC[4];
    #pragma unroll
    for (int n=0;n<4;n++){
      int c = n*16+fr;
      ciC[n] = c/7; cjC[n] = c - ciC[n]*7;
      gC[n] = grp[c]; cvC[n] = (c<49);
    }
    // bias + mask + softmax, in place
    #pragma unroll
    for (int m=0;m<4;m++){
      #pragma unroll
      for (int i=0;i<4;i++){
        int r = m*16 + fg*4 + i;
        int rv = (r<49);
        int ri = r/7, rj = r - ri*7;
        int gr = grp[r];
        float mxv = -3e30f;
        #pragma unroll
        for (int n=0;n<4;n++){
          float s;
          if (rv && cvC[n]){
            int dr = ri - ciC[n] + 6, dc = rj - cjC[n] + 6;
            s = sc[m][n][i]*SCALE + lb[wid][dr*13+dc];
            if (gr != gC[n]) s -= 100.f;
          } else s = -3e30f;
          sc[m][n][i] = s;
          mxv = fmaxf(mxv, s);
        }
        #pragma unroll
        for (int off=1;off<16;off<<=1) mxv = fmaxf(mxv, __shfl_xor(mxv, off));
        float sum = 0.f;
        #pragma unroll
        for (int n=0;n<4;n++){
          float e = __expf(sc[m][n][i]-mxv);
          sc[m][n][i] = e; sum += e;
        }
        #pragma unroll
        for (int off=1;off<16;off<<=1) sum += __shfl_xor(sum, off);
        float inv = 1.f/sum;
        #pragma unroll
        for (int n=0;n<4;n++)
          Pl[wid][r][n*16+fr] = f2bf(sc[m][n][i]*inv);
      }
    }
    __syncthreads();   // (2) P visible

    // O = P * V : A-frags from Pl, B-frags from Vt
    short8 pa[4][2], vb[2][2];
    #pragma unroll
    for (int m=0;m<4;m++)
      #pragma unroll
      for (int ks=0;ks<2;ks++)
        pa[m][ks] = *(const short8*)&Pl[wid][m*16+fr][ks*32+fg*8];
    #pragma unroll
    for (int n2=0;n2<2;n2++)
      #pragma unroll
      for (int ks=0;ks<2;ks++)
        vb[n2][ks] = *(const short8*)&Vt[wid][n2*16+fr][ks*32+fg*8];
    floatx4 oc[4][2];
    #pragma unroll
    for (int m=0;m<4;m++)
      #pragma unroll
      for (int n2=0;n2<2;n2++){
        oc[m][n2] = (floatx4){0.f,0.f,0.f,0.f};
        #pragma unroll
        for (int ks=0;ks<2;ks++)
          oc[m][n2] = __builtin_amdgcn_mfma_f32_16x16x32_bf16(pa[m][ks], vb[n2][ks], oc[m][n2], 0,0,0);
      }
    #pragma unroll
    for (int m=0;m<4;m++){
      #pragma unroll
      for (int i=0;i<4;i++){
        int r = m*16 + fg*4 + i;
        if (r < 49){
          #pragma unroll
          for (int n2=0;n2<2;n2++)
            attnout[(tbase+r)*384 + h*32 + n2*16 + fr] = f2bf(oc[m][n2][i]);
        }
      }
    }
    __syncthreads();   // (3) Vt reads done before next head's staging
  }
}

extern "C" void kernel_launch(void* const* d_in, const int* in_sizes, int n_in,
                              void* d_out, int out_size, void* d_ws, size_t ws_size,
                              hipStream_t stream)
{
  const float* x      = (const float*)d_in[0];
  const float* n1g    = (const float*)d_in[1];
  const float* n1b    = (const float*)d_in[2];
  const float* qkv_w  = (const float*)d_in[3];
  const float* qkv_b  = (const float*)d_in[4];
  const float* relb   = (const float*)d_in[5];
  const float* proj_w = (const float*)d_in[6];
  const float* proj_b = (const float*)d_in[7];
  const float* n2g    = (const float*)d_in[8];
  const float* n2b    = (const float*)d_in[9];
  const float* fc1_w  = (const float*)d_in[10];
  const float* fc1_b  = (const float*)d_in[11];
  const float* fc2_w  = (const float*)d_in[12];
  const float* fc2_b  = (const float*)d_in[13];

  char* ws = (char*)d_ws;
  const size_t SZ_XW  = (size_t)NTOK*CCH*2;      // 38,535,168  (xw, later hin)
  const size_t SZ_QKV = (size_t)NTOK*1152*2;     // 115,605,504 (qkv, later h low part)
  const size_t SZ_ATT = SZ_XW;                   // attnout, later h high part
  const size_t SZ_Y   = (size_t)NTOK*CCH*4;      // 77,070,336

  short* xw    = (short*)(ws);
  short* qkvb  = (short*)(ws + SZ_XW);
  short* att   = (short*)(ws + SZ_XW + SZ_QKV);
  float* y     = (float*)(ws + SZ_XW + SZ_QKV + SZ_ATT);
  short* wbuf  = (short*)(ws + SZ_XW + SZ_QKV + SZ_ATT + SZ_Y);
  short* qkvWt = wbuf;                           // [1152][384]
  short* projWt= qkvWt + (size_t)1152*384;       // [384][384]
  short* fc1Wt = projWt + (size_t)384*384;       // [1536][384]
  short* fc2Wt = fc1Wt + (size_t)1536*384;       // [384][1536]
  short* hbuf  = qkvb;                           // [NTOK][1536] (reuses qkv+att)
  short* hin   = xw;                             // [NTOK][384]  (reuses xw)

  wtconv<<<dim3((384*1152+255)/256), dim3(256), 0, stream>>>(qkv_w, qkvWt, 384, 1152);
  wtconv<<<dim3((384*384 +255)/256), dim3(256), 0, stream>>>(proj_w, projWt, 384, 384);
  wtconv<<<dim3((384*1536+255)/256), dim3(256), 0, stream>>>(fc1_w, fc1Wt, 384, 1536);
  wtconv<<<dim3((1536*384+255)/256), dim3(256), 0, stream>>>(fc2_w, fc2Wt, 1536, 384);

  ln_kernel<1><<<dim3(NTOK/4), dim3(256), 0, stream>>>(x, n1g, n1b, xw);
  gemm_bf16<0><<<dim3(1152/128, NTOK/128), dim3(256), 0, stream>>>(xw, qkvWt, qkv_b, nullptr, qkvb, NTOK, 1152, 384);
  attn_mfma<<<dim3(NBATCH*NW), dim3(256), 0, stream>>>(qkvb, relb, att);
  gemm_bf16<1><<<dim3(384/128, NTOK/128), dim3(256), 0, stream>>>(att, projWt, proj_b, x, y, NTOK, 384, 384);
  ln_kernel<0><<<dim3(NTOK/4), dim3(256), 0, stream>>>(y, n2g, n2b, hin);
  gemm_bf16<2><<<dim3(1536/128, NTOK/128), dim3(256), 0, stream>>>(hin, fc1Wt, fc1_b, nullptr, hbuf, NTOK, 1536, 384);
  gemm_bf16<3><<<dim3(384/128, NTOK/128), dim3(256), 0, stream>>>(hbuf, fc2Wt, fc2_b, y, d_out, NTOK, 384, 1536);
}